// Round 4
// baseline (736.920 us; speedup 1.0000x reference)
//
#include <hip/hip_runtime.h>

// x: (8,32,512,512) f32; A: 8x8 DCT; mask: 8x8 (low0 -> single nonzero).
// Per 8x8 tile X: L = A^T * (mask o (A * X * A^T)) * A ; out = (L, X - L).
// One thread per tile; mask-sparse rank-1 accumulation (wave-uniform branches).
// Pure 3-stream memory-bound kernel: 256 MiB read + 512 MiB write, no reuse
// -> nontemporal hints on all streams to avoid L2/L3 pollution.
// NOTE: __builtin_nontemporal_* requires a native clang vector type, not
// HIP's float4 struct -> use ext_vector_type(4).

typedef float f32x4 __attribute__((ext_vector_type(4)));

#define IMG_W 512u
#define HALF_ELEMS 67108864u     // 8*32*512*512

__global__ __launch_bounds__(256) void dct_lowpass_kernel(
    const float* __restrict__ x,
    const float* __restrict__ A,
    const float* __restrict__ mask,
    float* __restrict__ xlow,
    float* __restrict__ xhigh)
{
    const unsigned gid = blockIdx.x * 256u + threadIdx.x;  // tile id
    const unsigned nc  = gid >> 12;          // image (n*c) index
    const unsigned rem = gid & 4095u;
    const unsigned bh  = rem >> 6;           // block row
    const unsigned bw  = rem & 63u;          // block col
    const size_t base = ((size_t)nc * 512u + bh * 8u) * 512u + bw * 8u;

    // Load tile X (8 rows; per row 2x 16B, 32B-aligned). Nontemporal:
    // streamed once, never reused from cache.
    float X[8][8];
#pragma unroll
    for (int r = 0; r < 8; ++r) {
        const f32x4* p = reinterpret_cast<const f32x4*>(x + base + (size_t)r * IMG_W);
        f32x4 a = __builtin_nontemporal_load(p);
        f32x4 b = __builtin_nontemporal_load(p + 1);
        X[r][0] = a.x; X[r][1] = a.y; X[r][2] = a.z; X[r][3] = a.w;
        X[r][4] = b.x; X[r][5] = b.y; X[r][6] = b.z; X[r][7] = b.w;
    }

    float L[8][8];
#pragma unroll
    for (int j = 0; j < 8; ++j)
#pragma unroll
        for (int l = 0; l < 8; ++l) L[j][l] = 0.f;

    // Sparse-mask accumulation. mask/A accesses are wave-uniform with
    // compile-time offsets -> scalar (SGPR) loads; branches are uniform.
#pragma unroll
    for (int i = 0; i < 8; ++i) {
#pragma unroll
        for (int k = 0; k < 8; ++k) {
            const float m = mask[i * 8 + k];
            if (m != 0.0f) {
                // c = sum_j A[i,j] * (sum_l X[j,l] * A[k,l])
                float c = 0.f;
#pragma unroll
                for (int j = 0; j < 8; ++j) {
                    float r = 0.f;
#pragma unroll
                    for (int l = 0; l < 8; ++l) r = fmaf(X[j][l], A[k * 8 + l], r);
                    c = fmaf(A[i * 8 + j], r, c);
                }
                c *= m;
                // L[j][l] += c * A[i,j] * A[k,l]
#pragma unroll
                for (int j = 0; j < 8; ++j) {
                    const float cj = c * A[i * 8 + j];
#pragma unroll
                    for (int l = 0; l < 8; ++l)
                        L[j][l] = fmaf(cj, A[k * 8 + l], L[j][l]);
                }
            }
        }
    }

    // Write xlow = L, xhigh = X - L (nontemporal, 2x 16B per row each).
#pragma unroll
    for (int r = 0; r < 8; ++r) {
        f32x4 lo0 = { L[r][0], L[r][1], L[r][2], L[r][3] };
        f32x4 lo1 = { L[r][4], L[r][5], L[r][6], L[r][7] };
        f32x4 hi0 = { X[r][0] - L[r][0], X[r][1] - L[r][1],
                      X[r][2] - L[r][2], X[r][3] - L[r][3] };
        f32x4 hi1 = { X[r][4] - L[r][4], X[r][5] - L[r][5],
                      X[r][6] - L[r][6], X[r][7] - L[r][7] };
        f32x4* pl = reinterpret_cast<f32x4*>(xlow + base + (size_t)r * IMG_W);
        f32x4* ph = reinterpret_cast<f32x4*>(xhigh + base + (size_t)r * IMG_W);
        __builtin_nontemporal_store(lo0, pl);
        __builtin_nontemporal_store(lo1, pl + 1);
        __builtin_nontemporal_store(hi0, ph);
        __builtin_nontemporal_store(hi1, ph + 1);
    }
}

extern "C" void kernel_launch(void* const* d_in, const int* in_sizes, int n_in,
                              void* d_out, int out_size, void* d_ws, size_t ws_size,
                              hipStream_t stream) {
    const float* x    = (const float*)d_in[0];
    const float* A    = (const float*)d_in[1];
    const float* mask = (const float*)d_in[2];
    float* xlow  = (float*)d_out;
    float* xhigh = (float*)d_out + HALF_ELEMS;

    dim3 grid(4096);   // 1,048,576 tiles / 256 threads per block
    dim3 block(256);
    hipLaunchKernelGGL(dct_lowpass_kernel, grid, block, 0, stream,
                       x, A, mask, xlow, xhigh);
}

// Round 5
// 692.649 us; speedup vs baseline: 1.0639x; 1.0639x over previous
//
#include <hip/hip_runtime.h>

// x: (8,32,512,512) f32; A: 8x8 DCT; mask: 8x8 (low0 -> single nonzero).
// Per 8x8 tile X: L = A^T * (mask o (A * X * A^T)) * A ; out = (L, X - L).
//
// Layout: one LANE owns an 8-row x 4-col HALF-tile. Consecutive lanes then
// map to consecutive 16B chunks of each image row -> every global load/store
// is fully dense (64 lanes x 16B = 1KB contiguous per instruction), matching
// the 6.3 TB/s copy-benchmark pattern. Tile halves pair up as lanes (2t,2t+1);
// the DCT coefficient c_ik = a_i X a_k^T is combined with one shfl_xor(.,1).
// Mask-sparse rank-1 accumulation keeps compute negligible for 'low0'.

typedef float f32x4 __attribute__((ext_vector_type(4)));

#define HALF_ELEMS 67108864u     // 8*32*512*512

__global__ __launch_bounds__(256, 4) void dct_lowpass_kernel(
    const float* __restrict__ x,
    const float* __restrict__ A,
    const float* __restrict__ mask,
    float* __restrict__ xlow,
    float* __restrict__ xhigh)
{
    const unsigned T   = blockIdx.x * 256u + threadIdx.x;  // half-tile id
    const unsigned nc  = T >> 13;          // image idx (8192 half-tiles/image)
    const unsigned rem = T & 8191u;
    const unsigned bh  = rem >> 7;         // block row (128 half-tiles per block-row)
    const unsigned wi  = rem & 127u;       // half-tile idx within block-row
    const unsigned half = T & 1u;          // 0: cols 0-3, 1: cols 4-7 of the tile
    const size_t rowbase = ((size_t)nc * 512u + bh * 8u) * 512u + wi * 4u;

    // Load half-tile: 8 rows x 16B, dense across the wave per row.
    float X[8][4];
#pragma unroll
    for (int r = 0; r < 8; ++r) {
        f32x4 v = *reinterpret_cast<const f32x4*>(x + rowbase + (size_t)r * 512u);
        X[r][0] = v.x; X[r][1] = v.y; X[r][2] = v.z; X[r][3] = v.w;
    }

    float L[8][4];
#pragma unroll
    for (int r = 0; r < 8; ++r)
#pragma unroll
        for (int l = 0; l < 4; ++l) L[r][l] = 0.f;

    // Sparse-mask accumulation; mask/A reads are wave-uniform (SGPR),
    // branches wave-uniform. Divergent 'half' handled by cndmask selects.
#pragma unroll
    for (int i = 0; i < 8; ++i) {
#pragma unroll
        for (int k = 0; k < 8; ++k) {
            const float m = mask[i * 8 + k];
            if (m != 0.0f) {
                // ak[l] = A[k][half*4 + l]  (select between two SGPR values)
                float ak[4];
#pragma unroll
                for (int l = 0; l < 4; ++l)
                    ak[l] = half ? A[k * 8 + 4 + l] : A[k * 8 + l];

                // partial c over this lane's 4 columns, then pair-combine
                float cp = 0.f;
#pragma unroll
                for (int j = 0; j < 8; ++j) {
                    float rr = 0.f;
#pragma unroll
                    for (int l = 0; l < 4; ++l) rr = fmaf(X[j][l], ak[l], rr);
                    cp = fmaf(A[i * 8 + j], rr, cp);
                }
                const float c = (cp + __shfl_xor(cp, 1)) * m;

                // L[r][l] += c * A[i][r] * A[k][half*4+l]
#pragma unroll
                for (int r = 0; r < 8; ++r) {
                    const float cr = c * A[i * 8 + r];
#pragma unroll
                    for (int l = 0; l < 4; ++l)
                        L[r][l] = fmaf(cr, ak[l], L[r][l]);
                }
            }
        }
    }

    // Store xlow / xhigh: dense 1KB per instruction per row across the wave.
#pragma unroll
    for (int r = 0; r < 8; ++r) {
        f32x4 lo = { L[r][0], L[r][1], L[r][2], L[r][3] };
        f32x4 hi = { X[r][0] - L[r][0], X[r][1] - L[r][1],
                     X[r][2] - L[r][2], X[r][3] - L[r][3] };
        *reinterpret_cast<f32x4*>(xlow  + rowbase + (size_t)r * 512u) = lo;
        *reinterpret_cast<f32x4*>(xhigh + rowbase + (size_t)r * 512u) = hi;
    }
}

extern "C" void kernel_launch(void* const* d_in, const int* in_sizes, int n_in,
                              void* d_out, int out_size, void* d_ws, size_t ws_size,
                              hipStream_t stream) {
    const float* x    = (const float*)d_in[0];
    const float* A    = (const float*)d_in[1];
    const float* mask = (const float*)d_in[2];
    float* xlow  = (float*)d_out;
    float* xhigh = (float*)d_out + HALF_ELEMS;

    dim3 grid(8192);   // 2,097,152 half-tiles / 256 threads
    dim3 block(256);
    hipLaunchKernelGGL(dct_lowpass_kernel, grid, block, 0, stream,
                       x, A, mask, xlow, xhigh);
}